// Round 6
// baseline (1220.693 us; speedup 1.0000x reference)
//
#include <hip/hip_runtime.h>
#include <math.h>

#define N_NODES 20000
#define E_EDGES 200000
#define M1 60000            // layer-1 node count (3*N)
#define TE 16               // edges per block in fused kernel

typedef __attribute__((ext_vector_type(8))) short short8;
typedef __attribute__((ext_vector_type(4))) float f32x4;

// float -> bf16 (round-to-nearest-even), bit-level
__device__ __forceinline__ unsigned short f2bf(float f) {
    union { float f; unsigned int u; } v; v.f = f;
    unsigned int r = v.u + 0x7fffu + ((v.u >> 16) & 1u);
    return (unsigned short)(r >> 16);
}
__device__ __forceinline__ float bf2f(unsigned short u) {
    union { unsigned int u; float f; } v; v.u = ((unsigned int)u) << 16;
    return v.f;
}

// load 8 consecutive fp32 from global, pack to 8 bf16 (one MFMA A-frag slice)
__device__ __forceinline__ short8 ldA(const float* p) {
    float4 f0 = *(const float4*)p;
    float4 f1 = *(const float4*)(p + 4);
    short8 r;
    r[0] = (short)f2bf(f0.x); r[1] = (short)f2bf(f0.y);
    r[2] = (short)f2bf(f0.z); r[3] = (short)f2bf(f0.w);
    r[4] = (short)f2bf(f1.x); r[5] = (short)f2bf(f1.y);
    r[6] = (short)f2bf(f1.z); r[7] = (short)f2bf(f1.w);
    return r;
}

// ---------------------------------------------------------------------------
// GEMM: C[M,256] = X[M,K] @ W[K,256]  (fp32)
// ---------------------------------------------------------------------------
template<int K>
__global__ __launch_bounds__(256) void gemm_proj(const float* __restrict__ X,
                                                 const float* __restrict__ W,
                                                 float* __restrict__ C) {
    __shared__ float Xs[16][K];
    const int row0 = blockIdx.x * 16;
    const int tid = threadIdx.x;
    for (int i4 = tid; i4 < 16 * K / 4; i4 += 256) {
        int r = i4 / (K / 4), kq = i4 - r * (K / 4);
        ((float4*)&Xs[r][0])[kq] = ((const float4*)(X + (size_t)(row0 + r) * K))[kq];
    }
    __syncthreads();
    const int rg = tid >> 6;
    const int j0 = (tid & 63) * 4;
    float acc[4][4];
#pragma unroll
    for (int r = 0; r < 4; ++r)
#pragma unroll
        for (int t = 0; t < 4; ++t) acc[r][t] = 0.f;
#pragma unroll 4
    for (int k = 0; k < K; ++k) {
        float4 wq = *(const float4*)(W + (size_t)k * 256 + j0);
#pragma unroll
        for (int r = 0; r < 4; ++r) {
            float xv = Xs[rg * 4 + r][k];
            acc[r][0] = fmaf(xv, wq.x, acc[r][0]);
            acc[r][1] = fmaf(xv, wq.y, acc[r][1]);
            acc[r][2] = fmaf(xv, wq.z, acc[r][2]);
            acc[r][3] = fmaf(xv, wq.w, acc[r][3]);
        }
    }
#pragma unroll
    for (int r = 0; r < 4; ++r)
        *(float4*)(C + (size_t)(row0 + rg * 4 + r) * 256 + j0) =
            make_float4(acc[r][0], acc[r][1], acc[r][2], acc[r][3]);
}

// ---------------------------------------------------------------------------
// Old-path helpers (fallback when ws is small)
// ---------------------------------------------------------------------------
__global__ void init_x1(const float* __restrict__ proj0,
                        const float* __restrict__ theta,
                        const float* __restrict__ bias,
                        float* __restrict__ x1) {
    int idx = blockIdx.x * 256 + threadIdx.x;
    if (idx >= N_NODES * 256) return;
    int c = idx & 255;
    float v = theta[c] * proj0[idx] + bias[c];
    x1[idx] = v;
    x1[N_NODES * 256 + idx] = v;
    x1[2 * N_NODES * 256 + idx] = v;
}

__global__ void init_out(const float* __restrict__ proj1,
                         const float* __restrict__ theta,
                         const float* __restrict__ bias,
                         float* __restrict__ out) {
    int idx = blockIdx.x * 256 + threadIdx.x;
    if (idx >= M1 * 64) return;
    int v = idx >> 6, f = idx & 63;
    float s = 0.f;
#pragma unroll
    for (int h = 0; h < 4; ++h) s += theta[h * 64 + f] * proj1[v * 256 + h * 64 + f];
    float val = 0.25f * s + bias[f];
    out[idx] = val;
    out[M1 * 64 + idx] = val;
    out[2 * M1 * 64 + idx] = val;
}

__global__ void sigmoid_k(float4* __restrict__ x, int n4) {
    int i = blockIdx.x * 256 + threadIdx.x;
    if (i >= n4) return;
    float4 v = x[i];
    v.x = 1.f / (1.f + expf(-v.x));
    v.y = 1.f / (1.f + expf(-v.y));
    v.z = 1.f / (1.f + expf(-v.z));
    v.w = 1.f / (1.f + expf(-v.w));
    x[i] = v;
}

// ---------------------------------------------------------------------------
// Weight prep: W[K][64] fp32 -> WT[64][K] bf16 (transpose + convert)
// ---------------------------------------------------------------------------
__global__ void prep_wt(const float* __restrict__ W, unsigned short* __restrict__ WT,
                        int K) {
    int i = blockIdx.x * 256 + threadIdx.x;
    if (i >= 64 * K) return;
    int c = i / K, k = i - c * K;
    WT[i] = f2bf(W[k * 64 + c]);
}

// ---------------------------------------------------------------------------
// CSR build: cnt -> scan -> fill  (shared by both layers)
// ---------------------------------------------------------------------------
__global__ void zero_cnt(int* cnt) {
    int i = blockIdx.x * 256 + threadIdx.x;
    if (i < 3 * N_NODES) cnt[i] = 0;
}
__global__ void hist_k(const int* __restrict__ ei, int* __restrict__ cnt) {
    int i = blockIdx.x * 256 + threadIdx.x;
    if (i >= 3 * E_EDGES) return;
    int p = i / E_EDGES;
    atomicAdd(&cnt[p * N_NODES + ei[i]], 1);
}
__global__ __launch_bounds__(1024) void scan_k(const int* __restrict__ cnt,
                                               int* __restrict__ startA,
                                               int* __restrict__ cursor) {
    const int p = blockIdx.x;         // 0..2
    const int t = threadIdx.x;
    const int CH = (N_NODES + 1023) / 1024;  // 20
    int loc[CH];
    int own = 0;
    const int b0 = t * CH;
#pragma unroll
    for (int i = 0; i < CH; ++i) {
        int b = b0 + i;
        int c = (b < N_NODES) ? cnt[p * N_NODES + b] : 0;
        loc[i] = c; own += c;
    }
    __shared__ int sc[1024];
    sc[t] = own;
    __syncthreads();
    for (int off = 1; off < 1024; off <<= 1) {
        int vprev = (t >= off) ? sc[t - off] : 0;
        __syncthreads();
        sc[t] += vprev;
        __syncthreads();
    }
    int base = sc[t] - own;  // exclusive prefix
#pragma unroll
    for (int i = 0; i < CH; ++i) {
        int b = b0 + i;
        if (b < N_NODES) {
            startA[p * (N_NODES + 1) + b] = base;
            cursor[p * N_NODES + b] = base;
            base += loc[i];
        }
    }
    if (t == 1023) startA[p * (N_NODES + 1) + N_NODES] = sc[1023];
}
__global__ void fill_k(const int* __restrict__ ei, int* __restrict__ cursor,
                       int* __restrict__ idxA) {
    int i = blockIdx.x * 256 + threadIdx.x;
    if (i >= 3 * E_EDGES) return;
    int p = i / E_EDGES, e = i - p * E_EDGES;
    int v = ei[i];
    int pos = atomicAdd(&cursor[p * N_NODES + v], 1);
    idxA[p * E_EDGES + pos] = e;
}

// ---------------------------------------------------------------------------
// Pair MLP core (shared): a1 = leaky(concat(A0,A1)@eW1+eb1); a2 = a1@eW2.
// ---------------------------------------------------------------------------
__device__ __forceinline__ void pair_mlp(const short8 A0[2], const short8 A1[2],
                                         const unsigned short* __restrict__ eW1t,
                                         const unsigned short* __restrict__ eW2t,
                                         const float eb1c[4],
                                         unsigned short* nb,
                                         int g, int t, int ko, f32x4 a2[4]) {
    const f32x4 z = {0.f, 0.f, 0.f, 0.f};
    f32x4 a1[4] = {z, z, z, z};
#pragma unroll
    for (int half = 0; half < 2; ++half) {
#pragma unroll
        for (int ks = 0; ks < 2; ++ks) {
            short8 a = half ? A1[ks] : A0[ks];
#pragma unroll
            for (int f = 0; f < 4; ++f) {
                short8 b = *(const short8*)(eW1t + (16 * f + t) * 128 + half * 64 + ks * 32 + ko);
                a1[f] = __builtin_amdgcn_mfma_f32_16x16x32_bf16(a, b, a1[f], 0, 0, 0);
            }
        }
    }
#pragma unroll
    for (int f = 0; f < 4; ++f) {
        const int col = 16 * f + t;
#pragma unroll
        for (int r = 0; r < 4; ++r) {
            const int row = 4 * g + r;
            float hv = a1[f][r] + eb1c[f];
            hv = (hv >= 0.f) ? hv : 0.2f * hv;
            const int chunk = (col >> 3) ^ (row & 7);
            nb[row * 64 + chunk * 8 + (col & 7)] = f2bf(hv);
        }
    }
#pragma unroll
    for (int f = 0; f < 4; ++f) a2[f] = z;
#pragma unroll
    for (int ks = 0; ks < 2; ++ks) {
        const int chunk = (ks * 4 + g) ^ (t & 7);
        short8 a = *(const short8*)(nb + t * 64 + chunk * 8);
#pragma unroll
        for (int f = 0; f < 4; ++f) {
            short8 b = *(const short8*)(eW2t + (16 * f + t) * 64 + ks * 32 + ko);
            a2[f] = __builtin_amdgcn_mfma_f32_16x16x32_bf16(a, b, a2[f], 0, 0, 0);
        }
    }
}

// old path: atomic scatter
template<int LAYER>
__device__ __forceinline__ void do_pair(int p,
                                        const short8 A0[2], const short8 A1[2],
                                        const unsigned short* __restrict__ eW1t,
                                        const unsigned short* __restrict__ eW2t,
                                        const float eb1c[4], const float eb2c[4],
                                        const float alpha[4],
                                        unsigned short* nb,
                                        int g, int t, int ko, int vtp,
                                        float* __restrict__ out) {
    f32x4 a2[4];
    pair_mlp(A0, A1, eW1t, eW2t, eb1c, nb, g, t, ko, a2);
    if (LAYER == 0) {
#pragma unroll
        for (int f = 0; f < 4; ++f) {
            float* dst = out + ((size_t)(p * N_NODES + vtp)) * 256 + 16 * f + t;
#pragma unroll
            for (int r = 0; r < 4; ++r)
                atomicAdd(dst + r * 64, alpha[r] * (a2[f][r] + eb2c[f]));
        }
    } else {
#pragma unroll
        for (int f = 0; f < 4; ++f) {
            float s = 0.f;
#pragma unroll
            for (int r = 0; r < 4; ++r) s += alpha[r] * (a2[f][r] + eb2c[f]);
            atomicAdd(out + ((size_t)(p * M1 + vtp)) * 64 + 16 * f + t, 0.25f * s);
        }
    }
}

// new path: dense z write.  LAYER0: bf16, lane-permuted pos s=16t+4r+f
// (16 contiguous bf16 per lane = two short8 stores). LAYER1: fp32 logical.
template<int LAYER>
__device__ __forceinline__ void do_pair_dense(int p,
                                              const short8 A0[2], const short8 A1[2],
                                              const unsigned short* __restrict__ eW1t,
                                              const unsigned short* __restrict__ eW2t,
                                              const float eb1c[4], const float eb2c[4],
                                              const float alpha[4],
                                              unsigned short* nb,
                                              int g, int t, int ko, int ec,
                                              void* __restrict__ zbuf) {
    f32x4 a2[4];
    pair_mlp(A0, A1, eW1t, eW2t, eb1c, nb, g, t, ko, a2);
    if (LAYER == 0) {
        unsigned short* zr = (unsigned short*)zbuf
                           + ((size_t)(p * E_EDGES + ec)) * 256 + t * 16;
        short8 lo, hi;
#pragma unroll
        for (int j = 0; j < 8; ++j) {
            int r = j >> 2, f = j & 3;
            lo[j] = (short)f2bf(alpha[r] * (a2[f][r] + eb2c[f]));
        }
#pragma unroll
        for (int j = 0; j < 8; ++j) {
            int r = 2 + (j >> 2), f = j & 3;
            hi[j] = (short)f2bf(alpha[r] * (a2[f][r] + eb2c[f]));
        }
        *(short8*)zr = lo;
        *(short8*)(zr + 8) = hi;
    } else {
        float* zr = (float*)zbuf + ((size_t)(p * E_EDGES + ec)) * 64;
#pragma unroll
        for (int f = 0; f < 4; ++f) {
            float s = 0.f;
#pragma unroll
            for (int r = 0; r < 4; ++r) s += alpha[r] * (a2[f][r] + eb2c[f]);
            zr[16 * f + t] = 0.25f * s;
        }
    }
}

// ---------------------------------------------------------------------------
// Fused edge kernel (MFMA). Block: 16 edges, 4 waves; wave = 4 edges = 16 rows.
// DENSE=1: write z rows (no atomics).  DENSE=0: old atomic scatter.
// ---------------------------------------------------------------------------
template<int LAYER, int DENSE>
__global__ __launch_bounds__(256) void fused_edge(const float* __restrict__ proj,
                                                  const int* __restrict__ ei,
                                                  const unsigned short* __restrict__ aW1t,
                                                  const float* __restrict__ ab1,
                                                  const float* __restrict__ aW2,
                                                  const float* __restrict__ ab2,
                                                  const unsigned short* __restrict__ eW1t,
                                                  const float* __restrict__ eb1,
                                                  const unsigned short* __restrict__ eW2t,
                                                  const float* __restrict__ eb2,
                                                  float* __restrict__ out,
                                                  void* __restrict__ zbuf) {
    __shared__ __align__(16) unsigned short nb1[4][16 * 64];

    const int tid = threadIdx.x;
    const int w = tid >> 6, lane = tid & 63;
    const int g = lane >> 4, t = lane & 15;
    const int e0 = blockIdx.x * TE + w * 4;
    const int ko = g * 8;

    const int ea = e0 + (t >> 2);
    const int head = t & 3;
    const float* baseD = proj + (size_t)ei[ea] * 256 + head * 64;
    const float* baseM = proj + (size_t)ei[E_EDGES + ea] * 256 + head * 64;
    const float* baseS = proj + (size_t)ei[2 * E_EDGES + ea] * 256 + head * 64;

    const int ec = e0 + g;
    int vt0 = 0, vt1 = 0, vt2 = 0;
    if (!DENSE) { vt0 = ei[ec]; vt1 = ei[E_EDGES + ec]; vt2 = ei[2 * E_EDGES + ec]; }

    short8 aD[2], aM[2], aS[2];
#pragma unroll
    for (int ks = 0; ks < 2; ++ks) {
        aD[ks] = ldA(baseD + ks * 32 + ko);
        aM[ks] = ldA(baseM + ks * 32 + ko);
        aS[ks] = ldA(baseS + ks * 32 + ko);
    }

    float ab1c[4], aW2c[4], eb1c[4], eb2c[4];
#pragma unroll
    for (int f = 0; f < 4; ++f) {
        ab1c[f] = ab1[16 * f + t];
        aW2c[f] = aW2[16 * f + t];
        eb1c[f] = eb1[16 * f + t];
        eb2c[f] = eb2[16 * f + t];
    }

    // ---- attention MLP: H = [d|m|s] @ aW1  (K=192) ----
    const f32x4 z = {0.f, 0.f, 0.f, 0.f};
    f32x4 acc[4] = {z, z, z, z};
#pragma unroll
    for (int ks = 0; ks < 2; ++ks) {
        short8 a = aD[ks];
#pragma unroll
        for (int f = 0; f < 4; ++f) {
            short8 b = *(const short8*)(aW1t + (16 * f + t) * 192 + 0 * 64 + ks * 32 + ko);
            acc[f] = __builtin_amdgcn_mfma_f32_16x16x32_bf16(a, b, acc[f], 0, 0, 0);
        }
    }
#pragma unroll
    for (int ks = 0; ks < 2; ++ks) {
        short8 a = aM[ks];
#pragma unroll
        for (int f = 0; f < 4; ++f) {
            short8 b = *(const short8*)(aW1t + (16 * f + t) * 192 + 1 * 64 + ks * 32 + ko);
            acc[f] = __builtin_amdgcn_mfma_f32_16x16x32_bf16(a, b, acc[f], 0, 0, 0);
        }
    }
#pragma unroll
    for (int ks = 0; ks < 2; ++ks) {
        short8 a = aS[ks];
#pragma unroll
        for (int f = 0; f < 4; ++f) {
            short8 b = *(const short8*)(aW1t + (16 * f + t) * 192 + 2 * 64 + ks * 32 + ko);
            acc[f] = __builtin_amdgcn_mfma_f32_16x16x32_bf16(a, b, acc[f], 0, 0, 0);
        }
    }

    // ---- score epilogue: relu, @aW2 (col-reduce), +ab2, leaky, softmax ----
    float alpha[4];
    {
        float p_[4];
#pragma unroll
        for (int r = 0; r < 4; ++r) {
            float s = 0.f;
#pragma unroll
            for (int f = 0; f < 4; ++f) {
                float hv = fmaxf(acc[f][r] + ab1c[f], 0.f);
                s = fmaf(hv, aW2c[f], s);
            }
            p_[r] = s;
        }
#pragma unroll
        for (int off = 1; off < 16; off <<= 1) {
#pragma unroll
            for (int r = 0; r < 4; ++r) p_[r] += __shfl_xor(p_[r], off);
        }
        const float b2 = ab2[0];
        float sc[4];
#pragma unroll
        for (int r = 0; r < 4; ++r) {
            float v = p_[r] + b2;
            sc[r] = (v >= 0.f) ? v : 0.2f * v;
        }
        float mx = fmaxf(fmaxf(sc[0], sc[1]), fmaxf(sc[2], sc[3]));
        float ex[4], sum = 0.f;
#pragma unroll
        for (int r = 0; r < 4; ++r) { ex[r] = expf(sc[r] - mx); sum += ex[r]; }
        float inv = 1.f / sum;
#pragma unroll
        for (int r = 0; r < 4; ++r) alpha[r] = ex[r] * inv;
    }

    // ---- 3 pair MLPs (p0=(m,s)->d, p1=(d,s)->m, p2=(d,m)->s) ----
    unsigned short* nb = &nb1[w][0];
    if (DENSE) {
        do_pair_dense<LAYER>(0, aM, aS, eW1t, eW2t, eb1c, eb2c, alpha, nb, g, t, ko, ec, zbuf);
        do_pair_dense<LAYER>(1, aD, aS, eW1t, eW2t, eb1c, eb2c, alpha, nb, g, t, ko, ec, zbuf);
        do_pair_dense<LAYER>(2, aD, aM, eW1t, eW2t, eb1c, eb2c, alpha, nb, g, t, ko, ec, zbuf);
    } else {
        do_pair<LAYER>(0, aM, aS, eW1t, eW2t, eb1c, eb2c, alpha, nb, g, t, ko, vt0, out);
        do_pair<LAYER>(1, aD, aS, eW1t, eW2t, eb1c, eb2c, alpha, nb, g, t, ko, vt1, out);
        do_pair<LAYER>(2, aD, aM, eW1t, eW2t, eb1c, eb2c, alpha, nb, g, t, ko, vt2, out);
    }
}

// ---------------------------------------------------------------------------
// reduce0: x1[(p*N+v)*256+L] = sigmoid(theta0[L]*proj0[v][L]+bias0[L] + sum_e z0)
// one wave per (p,v) row; lane l reads stored pos [4l..4l+3] of each z row.
// ---------------------------------------------------------------------------
__global__ __launch_bounds__(256) void reduce0_k(const unsigned short* __restrict__ z0,
                                                 const int* __restrict__ startA,
                                                 const int* __restrict__ idxA,
                                                 const float* __restrict__ proj0,
                                                 const float* __restrict__ theta,
                                                 const float* __restrict__ bias,
                                                 float* __restrict__ x1) {
    const int w = threadIdx.x >> 6, l = threadIdx.x & 63;
    const int row = blockIdx.x * 4 + w;
    if (row >= 3 * N_NODES) return;
    const int p = row / N_NODES, v = row - p * N_NODES;
    const int s = startA[p * (N_NODES + 1) + v];
    const int e_ = startA[p * (N_NODES + 1) + v + 1];
    float acc[4] = {0.f, 0.f, 0.f, 0.f};
    for (int j = s; j < e_; ++j) {
        int e = idxA[p * E_EDGES + j];
        ushort4 u = *(const ushort4*)(z0 + ((size_t)(p * E_EDGES + e)) * 256 + l * 4);
        acc[0] += bf2f(u.x); acc[1] += bf2f(u.y);
        acc[2] += bf2f(u.z); acc[3] += bf2f(u.w);
    }
#pragma unroll
    for (int k = 0; k < 4; ++k) {
        // stored pos 4l+k  ->  logical col L = 64*(l&3) + 16*k + (l>>2)
        const int L = 64 * (l & 3) + 16 * k + (l >> 2);
        float base = theta[L] * proj0[(size_t)v * 256 + L] + bias[L];
        float val = base + acc[k];
        x1[(size_t)row * 256 + L] = 1.f / (1.f + expf(-val));
    }
}

// ---------------------------------------------------------------------------
// reduce1: out[(p*M1+v)*64+c] = 0.25*sum_h theta1*proj1 + bias1 + sum_e z1
// thread per (row, c4): 16 threads per row; float4 per edge.
// ---------------------------------------------------------------------------
__global__ __launch_bounds__(256) void reduce1_k(const float* __restrict__ z1,
                                                 const int* __restrict__ startA,
                                                 const int* __restrict__ idxA,
                                                 const float* __restrict__ proj1,
                                                 const float* __restrict__ theta,
                                                 const float* __restrict__ bias,
                                                 float* __restrict__ out) {
    const int gid = blockIdx.x * 256 + threadIdx.x;
    if (gid >= 3 * M1 * 16) return;
    const int row = gid >> 4, c4 = gid & 15;
    const int p = row / M1, v = row - p * M1;
    float4 acc = make_float4(0.f, 0.f, 0.f, 0.f);
    if (v < N_NODES) {
        const int s = startA[p * (N_NODES + 1) + v];
        const int e_ = startA[p * (N_NODES + 1) + v + 1];
        for (int j = s; j < e_; ++j) {
            int e = idxA[p * E_EDGES + j];
            float4 u = *(const float4*)(z1 + ((size_t)(p * E_EDGES + e)) * 64 + c4 * 4);
            acc.x += u.x; acc.y += u.y; acc.z += u.z; acc.w += u.w;
        }
    }
    float o[4] = {acc.x, acc.y, acc.z, acc.w};
#pragma unroll
    for (int c = 0; c < 4; ++c) {
        const int col = c4 * 4 + c;
        float b = 0.f;
#pragma unroll
        for (int h = 0; h < 4; ++h)
            b += theta[h * 64 + col] * proj1[(size_t)v * 256 + h * 64 + col];
        o[c] += 0.25f * b + bias[col];
    }
    *(float4*)(out + (size_t)row * 64 + c4 * 4) = make_float4(o[0], o[1], o[2], o[3]);
}

// ---------------------------------------------------------------------------
extern "C" void kernel_launch(void* const* d_in, const int* in_sizes, int n_in,
                              void* d_out, int out_size, void* d_ws, size_t ws_size,
                              hipStream_t stream) {
    (void)in_sizes; (void)n_in; (void)out_size;
    const float* x0       = (const float*)d_in[0];
    const int* ei         = (const int*)d_in[1];
    const float* p0_Wp    = (const float*)d_in[2];
    const float* p0_aW1   = (const float*)d_in[3];
    const float* p0_ab1   = (const float*)d_in[4];
    const float* p0_aW2   = (const float*)d_in[5];
    const float* p0_ab2   = (const float*)d_in[6];
    const float* p0_eW1   = (const float*)d_in[7];
    const float* p0_eb1   = (const float*)d_in[8];
    const float* p0_eW2   = (const float*)d_in[9];
    const float* p0_eb2   = (const float*)d_in[10];
    const float* p0_theta = (const float*)d_in[11];
    const float* p0_bias  = (const float*)d_in[12];
    const float* p1_Wp    = (const float*)d_in[13];
    const float* p1_aW1   = (const float*)d_in[14];
    const float* p1_ab1   = (const float*)d_in[15];
    const float* p1_aW2   = (const float*)d_in[16];
    const float* p1_ab2   = (const float*)d_in[17];
    const float* p1_eW1   = (const float*)d_in[18];
    const float* p1_eb1   = (const float*)d_in[19];
    const float* p1_eW2   = (const float*)d_in[20];
    const float* p1_eb2   = (const float*)d_in[21];
    const float* p1_theta = (const float*)d_in[22];
    const float* p1_bias  = (const float*)d_in[23];

    float* ws = (float*)d_ws;
    float* proj0 = ws;                 // 15,360,000 f (proj1 aliases)
    float* proj1 = ws;
    float* x1    = ws + 15360000;      // 15,360,000 f
    unsigned short* wt = (unsigned short*)(ws + 30720000);   // 49,152 us
    unsigned short* w0a  = wt;
    unsigned short* w0e1 = wt + 12288;
    unsigned short* w0e2 = wt + 20480;
    unsigned short* w1a  = wt + 24576;
    unsigned short* w1e1 = wt + 36864;
    unsigned short* w1e2 = wt + 45056;
    int* cnt    = (int*)(ws + 30744576);    // 60,000
    int* startA = cnt + 60000;              // 60,003
    int* cursor = startA + 60003;           // 60,000
    int* idxA   = cursor + 60000;           // 600,000
    float* zf   = ws + 31524592;            // z region: 76,800,000 f
    float* out = (float*)d_out;

    const size_t NEED = (size_t)(31524592 + 76800000) * 4;  // ~433.3 MB
    const int EB = E_EDGES / TE;  // 12500

    // ---- weight prep (bf16 transposes) ----
    prep_wt<<<(64 * 192 + 255) / 256, 256, 0, stream>>>(p0_aW1, w0a, 192);
    prep_wt<<<(64 * 128 + 255) / 256, 256, 0, stream>>>(p0_eW1, w0e1, 128);
    prep_wt<<<(64 * 64 + 255) / 256, 256, 0, stream>>>(p0_eW2, w0e2, 64);
    prep_wt<<<(64 * 192 + 255) / 256, 256, 0, stream>>>(p1_aW1, w1a, 192);
    prep_wt<<<(64 * 128 + 255) / 256, 256, 0, stream>>>(p1_eW1, w1e1, 128);
    prep_wt<<<(64 * 64 + 255) / 256, 256, 0, stream>>>(p1_eW2, w1e2, 64);

    if (ws_size >= NEED) {
        // ================= dense-z + CSR gather-reduce path =================
        zero_cnt<<<(3 * N_NODES + 255) / 256, 256, 0, stream>>>(cnt);
        hist_k<<<(3 * E_EDGES + 255) / 256, 256, 0, stream>>>(ei, cnt);
        scan_k<<<3, 1024, 0, stream>>>(cnt, startA, cursor);
        fill_k<<<(3 * E_EDGES + 255) / 256, 256, 0, stream>>>(ei, cursor, idxA);

        // ---- layer 0 ----
        gemm_proj<64><<<N_NODES / 16, 256, 0, stream>>>(x0, p0_Wp, proj0);
        fused_edge<0, 1><<<EB, 256, 0, stream>>>(proj0, ei, w0a, p0_ab1, p0_aW2, p0_ab2,
                                                 w0e1, p0_eb1, w0e2, p0_eb2,
                                                 nullptr, (void*)zf);
        reduce0_k<<<(3 * N_NODES + 3) / 4, 256, 0, stream>>>((const unsigned short*)zf,
                                                             startA, idxA, proj0,
                                                             p0_theta, p0_bias, x1);
        // ---- layer 1 ----
        gemm_proj<256><<<M1 / 16, 256, 0, stream>>>(x1, p1_Wp, proj1);
        fused_edge<1, 1><<<EB, 256, 0, stream>>>(proj1, ei, w1a, p1_ab1, p1_aW2, p1_ab2,
                                                 w1e1, p1_eb1, w1e2, p1_eb2,
                                                 nullptr, (void*)zf);
        reduce1_k<<<(3 * M1 * 16 + 255) / 256, 256, 0, stream>>>(zf, startA, idxA, proj1,
                                                                 p1_theta, p1_bias, out);
    } else {
        // ================= fallback: round-5 atomic path =================
        gemm_proj<64><<<N_NODES / 16, 256, 0, stream>>>(x0, p0_Wp, proj0);
        init_x1<<<(N_NODES * 256 + 255) / 256, 256, 0, stream>>>(proj0, p0_theta, p0_bias, x1);
        fused_edge<0, 0><<<EB, 256, 0, stream>>>(proj0, ei, w0a, p0_ab1, p0_aW2, p0_ab2,
                                                 w0e1, p0_eb1, w0e2, p0_eb2, x1, nullptr);
        sigmoid_k<<<(M1 * 64 + 255) / 256, 256, 0, stream>>>((float4*)x1, M1 * 64);
        gemm_proj<256><<<M1 / 16, 256, 0, stream>>>(x1, p1_Wp, proj1);
        init_out<<<(M1 * 64 + 255) / 256, 256, 0, stream>>>(proj1, p1_theta, p1_bias, out);
        fused_edge<1, 0><<<EB, 256, 0, stream>>>(proj1, ei, w1a, p1_ab1, p1_aW2, p1_ab2,
                                                 w1e1, p1_eb1, w1e2, p1_eb2, out, nullptr);
    }
}